// Round 11
// baseline (417.914 us; speedup 1.0000x reference)
//
#include <hip/hip_runtime.h>
#include <cstdint>

#define H 2048
#define NH 16
#define QLR 1536
#define KVLR 512
#define NOPE 128
#define ROPED 64
#define VH 128
#define QHD 192
#define SEQ 2048
#define NQH (NH*QHD)        // 3072
#define NKVC (NH*(NOPE+VH)) // 4096
#define NOV (NH*VH)         // 2048
#define KVAW_N (KVLR+ROPED) // 576
#define SCALE_L2E 0.10411755f   // 192^-0.5 * log2(e)
#define NSEG 4

typedef __attribute__((ext_vector_type(8))) short short8;
typedef __attribute__((ext_vector_type(4))) short short4v;
typedef __attribute__((ext_vector_type(4))) float floatx4;

__device__ __forceinline__ short f2bf(float x) {
  unsigned u = __builtin_bit_cast(unsigned, x);
  unsigned r = (u + 0x7FFFu + ((u >> 16) & 1u)) >> 16;
  return (short)(unsigned short)r;
}
__device__ __forceinline__ float bf2f(short s) {
  unsigned u = ((unsigned)(unsigned short)s) << 16;
  return __builtin_bit_cast(float, u);
}
__device__ __forceinline__ void g2l16(const void* g, void* l) {
  __builtin_amdgcn_global_load_lds(
      (const __attribute__((address_space(1))) void*)(uintptr_t)(g),
      (__attribute__((address_space(3))) void*)(uintptr_t)(l),
      16, 0, 0);
}

// Fragment-major tile layouts (all 1KB tiles = 512 shorts, lane-major:
// offset = (quad_f*16 + l16_f)*8 + pos):
//   qhm  : [h][qt=128][ks=6]   q rows x 32-dim slices (prescaled, roped)
//   knope: [h][kt=128][ks=4]   kv rows x 32-dim slices (nope dims)
//   kpe  : [kt=128][2]         kv rows x 32-dim rope slices (head-shared)
//   vT   : [h][dt=8][kb=64]    16 d-rows x 32-kv slices (transposed V)

// ---------------- fused fp32 -> bf16 convert ----------------
struct CvtArgs {
  const float* src[3];
  short* dst[3];
  int cum[4];
};
// small cvt: hs, q_a_w, kv_a_w (needed by GEMM1)
__global__ __launch_bounds__(256) void k_cvt_all(CvtArgs a, int total4) {
  int stride = gridDim.x * 256;
  for (int i = blockIdx.x * 256 + threadIdx.x; i < total4; i += stride) {
    int j = 0;
#pragma unroll
    for (int t = 1; t < 3; ++t) j += (i >= a.cum[t]);
    int loc = i - a.cum[j];
    float4 v = ((const float4*)a.src[j])[loc];
    short4v o;
    o.x = f2bf(v.x); o.y = f2bf(v.y); o.z = f2bf(v.z); o.w = f2bf(v.w);
    ((short4v*)a.dst[j])[loc] = o;
  }
}

// ------- 128x128 pipelined NT GEMM (BK=32, 3-ring, XCD-patch swizzle) -------
// R6-proven configuration. EPI=1 additionally hosts 256 converter blocks
// (bid >= 288) that grid-stride the q_b/kv_b/o_w fp32->bf16 conversion --
// those weights are consumed two kernels later, and GEMM1 runs at 1 block/CU
// with 12% HBM, so the conversion hides under it (R10 theory).
struct W3 {
  const float* src[3];
  short* dst[3];
  int cum[4];
};
template<int EPI>
__global__ __launch_bounds__(256) void k_gemm128(
    const short* __restrict__ A, const short* __restrict__ B,
    float* __restrict__ C, float* __restrict__ C2, int N, int K, W3 w3)
{
  __shared__ short As[3][4096];
  __shared__ short Bs[3][4096];
  const int tid = threadIdx.x;
  const int bid = blockIdx.x;

  if (EPI == 1 && bid >= 288) {       // converter blocks
    int cb = bid - 288;
    int stride = 256 * 256;
    for (int i = cb * 256 + tid; i < w3.cum[3]; i += stride) {
      int j = 0;
#pragma unroll
      for (int t = 1; t < 3; ++t) j += (i >= w3.cum[t]);
      int loc = i - w3.cum[j];
      float4 v = ((const float4*)w3.src[j])[loc];
      short4v o;
      o.x = f2bf(v.x); o.y = f2bf(v.y); o.z = f2bf(v.z); o.w = f2bf(v.w);
      ((short4v*)w3.dst[j])[loc] = o;
    }
    return;
  }

  const int lane = tid & 63;
  const int w = tid >> 6;
  const int wm = w & 1, wn = w >> 1;
  const int quad = lane >> 4, l16 = lane & 15;

  const int xcd = bid & 7, j = bid >> 3;
  int mi_, ni_;
  if (EPI == 0) {          // 256 = 8 xcd x (4m x 8n)
    mi_ = (xcd & 3) * 4 + (j & 3);
    ni_ = (xcd >> 2) * 8 + (j >> 2);
  } else {                 // 288 = 8 xcd x (4m x 9n); n==17 idle
    mi_ = (xcd & 3) * 4 + (j & 3);
    ni_ = (xcd >> 2) * 9 + (j >> 2);
    if (ni_ >= 17) return;
  }
  const int m0 = mi_ * 128, n0 = ni_ * 128;
  const int T = K >> 5;

  floatx4 acc[4][4] = {};

  auto issue = [&](int t, int buf) {
#pragma unroll
    for (int i = 0; i < 2; ++i) {
      int c = i*256 + tid;
      int row = c & 127, koct = c >> 7;
      g2l16(A + (size_t)(m0 + row)*K + t*32 + koct*8, As[buf] + (koct*128 + row)*8);
      g2l16(B + (size_t)(n0 + row)*K + t*32 + koct*8, Bs[buf] + (koct*128 + row)*8);
    }
  };

  issue(0, 0);
  issue(1, 1);
  int buf = 0;
  for (int t = 0; t < T; ++t) {
    if (t + 2 < T) {
      int nb = buf - 1; if (nb < 0) nb = 2;
      issue(t + 2, nb);
      asm volatile("s_waitcnt vmcnt(8)" ::: "memory");
    } else if (t + 1 < T) {
      asm volatile("s_waitcnt vmcnt(4)" ::: "memory");
    } else {
      asm volatile("s_waitcnt vmcnt(0)" ::: "memory");
    }
    asm volatile("s_barrier" ::: "memory");
    short8 af[4], bfr[4];
#pragma unroll
    for (int mi = 0; mi < 4; ++mi)
      af[mi] = *(const short8*)(As[buf] + (quad*128 + wm*64 + mi*16 + l16)*8);
#pragma unroll
    for (int ni = 0; ni < 4; ++ni)
      bfr[ni] = *(const short8*)(Bs[buf] + (quad*128 + wn*64 + ni*16 + l16)*8);
#pragma unroll
    for (int mi = 0; mi < 4; ++mi)
#pragma unroll
      for (int ni = 0; ni < 4; ++ni)
        acc[mi][ni] = __builtin_amdgcn_mfma_f32_16x16x32_bf16(af[mi], bfr[ni], acc[mi][ni], 0, 0, 0);
    asm volatile("s_barrier" ::: "memory");
    buf = buf + 1; if (buf > 2) buf = 0;
  }

#pragma unroll
  for (int mi = 0; mi < 4; ++mi) {
#pragma unroll
    for (int ni = 0; ni < 4; ++ni) {
      int col = n0 + wn*64 + ni*16 + l16;
#pragma unroll
      for (int r = 0; r < 4; ++r) {
        int row = m0 + wm*64 + mi*16 + quad*4 + r;
        if (EPI == 0) {
          C[(size_t)row*N + col] = acc[mi][ni][r];
        } else {
          if (col < QLR)                C[(size_t)row*QLR + col] = acc[mi][ni][r];
          else if (col < QLR + KVAW_N)  C2[(size_t)row*KVAW_N + (col - QLR)] = acc[mi][ni][r];
        }
      }
    }
  }
}

// -------- merged q_b + kv_b GEMM (BN=128, 3-ring, XCD-patch swizzle) --------
// R8-proven 2-barrier version (R9/R10's deeper-phase variants were null:
// drain-vmcnt schedules do not beat the 2-barrier loop; the counted-vmcnt
// pipeline needs the full m201 half-tile stagger, not attempted here).
// q part (384 = 8 x 4m x 12n), kv part (512 = 8 x 4m x 16n).
__global__ __launch_bounds__(256) void k_gemm2(
    const short* __restrict__ qlatn, const short* __restrict__ qbw,
    const short* __restrict__ kvln,  const short* __restrict__ kvbw,
    short* __restrict__ qhm, short* __restrict__ knope, short* __restrict__ vTd)
{
  __shared__ short As[3][4096];
  __shared__ short Bs[3][4096];
  const int tid = threadIdx.x;
  const int lane = tid & 63;
  const int w = tid >> 6;
  const int wm = w & 1, wn = w >> 1;
  const int quad = lane >> 4, l16 = lane & 15;
  int bid = blockIdx.x;
  const short *A, *B; int K, m0, n0; bool isq;
  if (bid < 384) {
    isq = true;  A = qlatn; B = qbw;  K = QLR;
    const int xcd = bid & 7, j = bid >> 3;          // j 0..47
    m0 = ((xcd & 3) * 4 + (j & 3)) * 128;           // m 0..15
    n0 = ((xcd >> 2) * 12 + (j >> 2)) * 128;        // n 0..23
  } else {
    int b2 = bid - 384; isq = false; A = kvln; B = kvbw; K = KVLR;
    const int xcd = b2 & 7, j = b2 >> 3;            // j 0..63
    m0 = ((xcd & 3) * 4 + (j & 3)) * 128;           // m 0..15
    n0 = ((xcd >> 2) * 16 + (j >> 2)) * 128;        // n 0..31
  }
  const int T = K >> 5;

  floatx4 acc[4][4] = {};

  auto issue = [&](int t, int buf) {
#pragma unroll
    for (int i = 0; i < 2; ++i) {
      int c = i*256 + tid;
      int row = c & 127, koct = c >> 7;
      g2l16(A + (size_t)(m0 + row)*K + t*32 + koct*8, As[buf] + (koct*128 + row)*8);
      g2l16(B + (size_t)(n0 + row)*K + t*32 + koct*8, Bs[buf] + (koct*128 + row)*8);
    }
  };

  issue(0, 0);
  issue(1, 1);
  int buf = 0;
  for (int t = 0; t < T; ++t) {
    if (t + 2 < T) {
      int nb = buf - 1; if (nb < 0) nb = 2;
      issue(t + 2, nb);
      asm volatile("s_waitcnt vmcnt(8)" ::: "memory");
    } else if (t + 1 < T) {
      asm volatile("s_waitcnt vmcnt(4)" ::: "memory");
    } else {
      asm volatile("s_waitcnt vmcnt(0)" ::: "memory");
    }
    asm volatile("s_barrier" ::: "memory");
    short8 af[4], bfr[4];
#pragma unroll
    for (int mi = 0; mi < 4; ++mi)
      af[mi] = *(const short8*)(As[buf] + (quad*128 + wm*64 + mi*16 + l16)*8);
#pragma unroll
    for (int ni = 0; ni < 4; ++ni)
      bfr[ni] = *(const short8*)(Bs[buf] + (quad*128 + wn*64 + ni*16 + l16)*8);
#pragma unroll
    for (int mi = 0; mi < 4; ++mi)
#pragma unroll
      for (int ni = 0; ni < 4; ++ni)
        acc[mi][ni] = __builtin_amdgcn_mfma_f32_16x16x32_bf16(af[mi], bfr[ni], acc[mi][ni], 0, 0, 0);
    asm volatile("s_barrier" ::: "memory");
    buf = buf + 1; if (buf > 2) buf = 0;
  }

  const int n064 = n0 + wn * 64;
  if (isq) {
    const int h = n064 / QHD;
    const bool ropew = (n064 % QHD) == 128;
    if (!ropew) {
      const int dbase = n064 - h * QHD;   // 0 or 64
#pragma unroll
      for (int mi = 0; mi < 4; ++mi) {
        const int qt = (m0 + wm*64 + mi*16) >> 4;
#pragma unroll
        for (int ni = 0; ni < 4; ++ni) {
          int d = dbase + ni*16 + l16;
          size_t tb = ((size_t)(h*128 + qt)*6 + (d>>5))*512
                    + (size_t)(((d>>3)&3)*16)*8 + (d&7);
#pragma unroll
          for (int r = 0; r < 4; ++r)
            qhm[tb + (quad*4 + r)*8] = f2bf(acc[mi][ni][r] * SCALE_L2E);
        }
      }
    } else {
#pragma unroll
      for (int ni = 0; ni < 2; ++ni) {
        int i = ni*16 + l16;                     // 0..31
        float fr = powf(10000.0f, -(float)i / 32.0f);
        const int qoff = ((i>>3)*16)*8 + (i&7);
#pragma unroll
        for (int mi = 0; mi < 4; ++mi) {
          const int qt = (m0 + wm*64 + mi*16) >> 4;
          size_t t4 = ((size_t)(h*128 + qt)*6 + 4)*512 + qoff;  // ks=4 (dims 128..159)
#pragma unroll
          for (int r = 0; r < 4; ++r) {
            int row = m0 + wm*64 + mi*16 + quad*4 + r;
            float ang = (float)row * fr;
            float cv, sv; __sincosf(ang, &sv, &cv);
            float x1 = acc[mi][ni][r], x2 = acc[mi][ni+2][r];
            qhm[t4 + (quad*4 + r)*8]       = f2bf((x1*cv - x2*sv) * SCALE_L2E);
            qhm[t4 + 512 + (quad*4 + r)*8] = f2bf((x2*cv + x1*sv) * SCALE_L2E); // ks=5
          }
        }
      }
    }
  } else {
    const bool isv = (n064 & 128) != 0;
    if (!isv) {
#pragma unroll
      for (int mi = 0; mi < 4; ++mi) {
        const int kt = (m0 + wm*64 + mi*16) >> 4;
#pragma unroll
        for (int ni = 0; ni < 4; ++ni) {
          int col = n064 + ni*16 + l16;
          int hh = col >> 8, d = col & 127;
          size_t tb = ((size_t)(hh*128 + kt)*4 + (d>>5))*512
                    + (size_t)(((d>>3)&3)*16)*8 + (d&7);
#pragma unroll
          for (int r = 0; r < 4; ++r)
            knope[tb + (quad*4 + r)*8] = f2bf(acc[mi][ni][r]);
        }
      }
    } else {
#pragma unroll
      for (int mi = 0; mi < 4; ++mi) {
        const int row0 = m0 + wm*64 + mi*16 + quad*4;   // kv row of r=0
        const int kb = row0 >> 5;
        const int voff = (((row0>>3)&3)*16)*8 + (row0 & 7); // row0%8 in {0,4}
#pragma unroll
        for (int ni = 0; ni < 4; ++ni) {
          int col = n064 + ni*16 + l16;
          int hh = col >> 8, dv = (col & 255) - 128;
          short4v pk;
          pk.x = f2bf(acc[mi][ni][0]); pk.y = f2bf(acc[mi][ni][1]);
          pk.z = f2bf(acc[mi][ni][2]); pk.w = f2bf(acc[mi][ni][3]);
          *(short4v*)(vTd + ((size_t)(hh*8 + (dv>>4))*64 + kb)*512
                          + voff + (dv & 15)*8) = pk;
        }
      }
    }
  }
}

// ---------------- merged RMS norms + rope_k ----------------
__global__ __launch_bounds__(256) void k_rms2(
    const float* __restrict__ qlat, const float* __restrict__ q_a_ln,
    short* __restrict__ qlatn,
    const float* __restrict__ kvlp, const float* __restrict__ kv_a_ln,
    short* __restrict__ kvln, short* __restrict__ kpe)
{
  int b = blockIdx.x;
  __shared__ float red[4];
  if (b < SEQ) {
    int row = b;
    const float* xr = qlat + (size_t)row * QLR;
    float s = 0.f;
    for (int i = threadIdx.x; i < QLR; i += 256) { float v = xr[i]; s += v*v; }
#pragma unroll
    for (int off = 1; off < 64; off <<= 1) s += __shfl_xor(s, off);
    if ((threadIdx.x & 63) == 0) red[threadIdx.x >> 6] = s;
    __syncthreads();
    float inv = rsqrtf((red[0]+red[1]+red[2]+red[3]) / (float)QLR + 1e-6f);
    for (int i = threadIdx.x; i < QLR; i += 256)
      qlatn[(size_t)row * QLR + i] = f2bf(xr[i] * inv * q_a_ln[i]);
  } else {
    int row = b - SEQ;
    const float* xr = kvlp + (size_t)row * KVAW_N;
    float s = 0.f;
    for (int i = threadIdx.x; i < KVLR; i += 256) { float v = xr[i]; s += v*v; }
#pragma unroll
    for (int off = 1; off < 64; off <<= 1) s += __shfl_xor(s, off);
    if ((threadIdx.x & 63) == 0) red[threadIdx.x >> 6] = s;
    __syncthreads();
    float inv = rsqrtf((red[0]+red[1]+red[2]+red[3]) / (float)KVLR + 1e-6f);
    for (int i = threadIdx.x; i < KVLR; i += 256)
      kvln[(size_t)row * KVLR + i] = f2bf(xr[i] * inv * kv_a_ln[i]);
    if (threadIdx.x < 32) {
      int i = threadIdx.x;
      float ang = (float)row * powf(10000.0f, -(float)i / 32.0f);
      float cv, sv; __sincosf(ang, &sv, &cv);
      float x1 = xr[KVLR + i], x2 = xr[KVLR + 32 + i];
      // fragment-major kpe: tile (row>>4)*2 + slice, lane (i>>3, row&15), pos i&7
      size_t t0 = (size_t)((row >> 4) * 2) * 512
                + (size_t)(((i >> 3) * 16) + (row & 15)) * 8 + (i & 7);
      kpe[t0]       = f2bf(x1*cv - x2*sv);   // slice 0: dims 0..31
      kpe[t0 + 512] = f2bf(x2*cv + x1*sv);   // slice 1: dims 32..63
    }
  }
}

// ------------- attention v9: 8-wave cooperative LDS-staged flash -------------
// 640 blocks; 8 waves x 16 q-rows (512 thr); K/kpe/V staged cooperatively via
// global_load_lds, double-buffered, prefetched 2 chunks ahead (counted vmcnt);
// defer-max (T13) skips the O-rescale when chunk max grew <= 8.
__device__ __constant__ unsigned char g_task[40] = {
  60,61,62,63, 56,57,58, 52,53,54, 48,49,50, 44,45,46,
  40,41, 36,37, 32,33, 28,29, 24, 20, 16, 12,
  59,42,25,8, 55,38,21,4, 51,34,17,0 };

__global__ __launch_bounds__(512) void k_attn8(
    const short* __restrict__ qhm,   // frag-major [NH][128][6] tiles, prescaled
    const short* __restrict__ knope, // frag-major [NH][128][4] tiles
    const short* __restrict__ kpe,   // frag-major [128][2] tiles
    const short* __restrict__ vT,    // frag-major [NH][8][64] tiles
    short* __restrict__ Opart,       // [NSEG][SEQ][NOV]
    float2* __restrict__ mlb)        // [NSEG][SEQ][NH]
{
  // LDS: 2 chunk buffers of 40KB (K 8192 | kpe 4096 | V 8192 shorts) + P.
  __shared__ short Ls[2][20480];
  __shared__ short Pl[8][16 * 72];
  const int tid = threadIdx.x;
  const int lane = tid & 63, w = tid >> 6;   // w 0..7
  const int quad = lane >> 4, l16 = lane & 15;
  const int b = blockIdx.x;
  const int h = b & 15;                 // head -> XCD-locked L2 locality
  const int qs2 = g_task[b >> 4];
  const int qb = qs2 >> 2, seg = qs2 & 3;
  const int cs = seg * 8;               // chunks of 64 kv
  const int cend0 = 2 * qb + 2;
  const int cend = (cend0 < cs + 8) ? cend0 : (cs + 8);
  const int qws = qb * 128 + w * 16;    // 16 q-rows per wave
  short* Plw = Pl[w];

  const short* qbase = qhm   + (size_t)h * (128*6*512);
  const short* kbase = knope + (size_t)h * (128*4*512);
  const short* vbase = vT    + (size_t)h * (8*64*512);

  const int qt0 = qws >> 4;             // q-tile index (16 rows)
  short8 qf[6];
#pragma unroll
  for (int ks = 0; ks < 6; ++ks)
    qf[ks] = *(const short8*)(qbase + ((size_t)qt0*6 + ks)*512 + lane*8);

  // stage chunk kc into buffer buf: 5 x 16B per thread (512 threads)
  auto issue = [&](int kc, int buf) {
    short* L = &Ls[buf][0];
    const short* ksrc = kbase + (size_t)kc * 8192;   // 4 kt-tiles x 4 slices
    const short* psrc = kpe   + (size_t)kc * 4096;   // 4 kt-tiles x 2 slices
#pragma unroll
    for (int i = 0; i < 2; ++i)
      g2l16(ksrc + (i*512 + tid)*8, L + (i*512 + tid)*8);
    g2l16(psrc + tid*8, L + 8192 + tid*8);
#pragma unroll
    for (int i = 0; i < 2; ++i) {
      int uv = i*512 + tid;
      int dt = uv >> 7, wi = uv & 127;
      g2l16(vbase + ((size_t)(dt*64 + kc*2))*512 + wi*8, L + 12288 + uv*8);
    }
  };

  issue(cs, 0);
  if (cs + 1 < cend) issue(cs + 1, 1);

  floatx4 oacc[8] = {};
  float m_i = -1e30f, l_i = 0.f;

  for (int kc = cs; kc < cend; ++kc) {
    if (kc + 1 < cend) asm volatile("s_waitcnt vmcnt(5)" ::: "memory");
    else               asm volatile("s_waitcnt vmcnt(0)" ::: "memory");
    asm volatile("s_barrier" ::: "memory");
    const short* Lb = &Ls[kc & 1][0];
    const int kv0 = kc * 64;

    // ---- S^T over 4 sub-tiles of 16 kv (one 16-row q tile) ----
    floatx4 s[4] = {};
#pragma unroll
    for (int mt = 0; mt < 4; ++mt) {
      const short* kr = Lb + mt*2048 + lane*8;
      const short* pr = Lb + 8192 + mt*1024 + lane*8;
      short8 kf0 = *(const short8*)(kr);
      short8 kf1 = *(const short8*)(kr + 512);
      short8 kf2 = *(const short8*)(kr + 1024);
      short8 kf3 = *(const short8*)(kr + 1536);
      short8 kf4 = *(const short8*)(pr);
      short8 kf5 = *(const short8*)(pr + 512);
      s[mt] = __builtin_amdgcn_mfma_f32_16x16x32_bf16(kf0, qf[0], s[mt], 0, 0, 0);
      s[mt] = __builtin_amdgcn_mfma_f32_16x16x32_bf16(kf1, qf[1], s[mt], 0, 0, 0);
      s[mt] = __builtin_amdgcn_mfma_f32_16x16x32_bf16(kf2, qf[2], s[mt], 0, 0, 0);
      s[mt] = __builtin_amdgcn_mfma_f32_16x16x32_bf16(kf3, qf[3], s[mt], 0, 0, 0);
      s[mt] = __builtin_amdgcn_mfma_f32_16x16x32_bf16(kf4, qf[4], s[mt], 0, 0, 0);
      s[mt] = __builtin_amdgcn_mfma_f32_16x16x32_bf16(kf5, qf[5], s[mt], 0, 0, 0);
    }

    // ---- softmax for the 64 kv (defer-max) ----
    const bool diag = (kv0 + 64 > qws);
    const int qg = qws + l16;
    float mx = -1e30f;
#pragma unroll
    for (int mt = 0; mt < 4; ++mt)
#pragma unroll
      for (int rr = 0; rr < 4; ++rr) {
        float v = s[mt][rr];
        if (diag) {
          int kvg = kv0 + mt*16 + quad*4 + rr;
          v = (kvg <= qg) ? v : -1e30f;
          s[mt][rr] = v;
        }
        mx = fmaxf(mx, v);
      }
    mx = fmaxf(mx, __shfl_xor(mx, 16));
    mx = fmaxf(mx, __shfl_xor(mx, 32));
    const bool skip = __all(mx - m_i <= 8.0f);   // wave-uniform
    float alpha = 1.0f;
    if (!skip) {
      float mnew = fmaxf(m_i, mx);
      alpha = exp2f(m_i - mnew);
      m_i = mnew;
    }
    float ssum = 0.f;
#pragma unroll
    for (int mt = 0; mt < 4; ++mt) {
      float p0 = exp2f(s[mt][0] - m_i);
      float p1 = exp2f(s[mt][1] - m_i);
      float p2 = exp2f(s[mt][2] - m_i);
      float p3 = exp2f(s[mt][3] - m_i);
      ssum += (p0 + p1) + (p2 + p3);
      short4v pk; pk.x = f2bf(p0); pk.y = f2bf(p1); pk.z = f2bf(p2); pk.w = f2bf(p3);
      *(short4v*)(Plw + l16*72 + mt*16 + quad*4) = pk;
    }
    ssum += __shfl_xor(ssum, 16);
    ssum += __shfl_xor(ssum, 32);
    l_i = l_i * alpha + ssum;
    if (!skip) {
#pragma unroll
      for (int dt = 0; dt < 8; ++dt)
#pragma unroll
        for (int rr = 0; rr < 4; ++rr) oacc[dt][rr] *= alpha;
    }

    // ---- O^T += V^T * P^T over 2 slices of 32 kv ----
#pragma unroll
    for (int sl = 0; sl < 2; ++sl) {
      short8 pf = *(const short8*)(Plw + l16*72 + sl*32 + quad*8);
#pragma unroll
      for (int dt = 0; dt < 8; ++dt) {
        short8 vf = *(const short8*)(Lb + 12288 + (dt*2 + sl)*512 + lane*8);
        oacc[dt] = __builtin_amdgcn_mfma_f32_16x16x32_bf16(vf, pf, oacc[dt], 0, 0, 0);
      }
    }

    asm volatile("s_barrier" ::: "memory");   // all waves done reading buf
    if (kc + 2 < cend) issue(kc + 2, kc & 1);
  }

  {
    float inv = (l_i > 0.f) ? 1.f / l_i : 0.f;
    int q = qws + l16;
    if (quad == 0)
      mlb[((size_t)seg * SEQ + q) * NH + h] = make_float2(m_i, l_i);
#pragma unroll
    for (int dt = 0; dt < 8; ++dt) {
      short4v pk;
      pk.x = f2bf(oacc[dt][0] * inv);
      pk.y = f2bf(oacc[dt][1] * inv);
      pk.z = f2bf(oacc[dt][2] * inv);
      pk.w = f2bf(oacc[dt][3] * inv);
      *(short4v*)(Opart + ((size_t)seg * SEQ + q) * NOV + h * VH + dt*16 + quad*4) = pk;
    }
  }
}

// ---------------- split-KV combiner ----------------
__global__ __launch_bounds__(256) void k_comb(
    const short* __restrict__ Opart, const float2* __restrict__ mlb,
    short* __restrict__ ob)
{
  int q = blockIdx.x;
  int hd0 = threadIdx.x * 8;
  int h = hd0 >> 7;
  int nact = (q >> 9) + 1;
  float2 mlv[NSEG];
  float M = -1e30f;
  for (int s = 0; s < nact; ++s) {
    mlv[s] = mlb[((size_t)s * SEQ + q) * NH + h];
    M = fmaxf(M, mlv[s].x);
  }
  float wgt[NSEG]; float L = 0.f;
  for (int s = 0; s < nact; ++s) {
    wgt[s] = mlv[s].y * exp2f(mlv[s].x - M);
    L += wgt[s];
  }
  float invL = 1.0f / L;
  float acc[8] = {};
  for (int s = 0; s < nact; ++s) {
    short8 o = *(const short8*)(Opart + ((size_t)s * SEQ + q) * NOV + hd0);
    float ws = wgt[s] * invL;
#pragma unroll
    for (int j = 0; j < 8; ++j) acc[j] += ws * bf2f(o[j]);
  }
  short8 rr;
#pragma unroll
  for (int j = 0; j < 8; ++j) rr[j] = f2bf(acc[j]);
  *(short8*)(ob + (size_t)q * NOV + hd0) = rr;
}

// ---------------- launch ----------------
extern "C" void kernel_launch(void* const* d_in, const int* in_sizes, int n_in,
                              void* d_out, int out_size, void* d_ws, size_t ws_size,
                              hipStream_t stream) {
  const float* hs      = (const float*)d_in[0];
  const float* q_a_w   = (const float*)d_in[1];
  const float* q_a_ln  = (const float*)d_in[2];
  const float* q_b_w   = (const float*)d_in[3];
  const float* kv_a_w  = (const float*)d_in[4];
  const float* kv_a_ln = (const float*)d_in[5];
  const float* kv_b_w  = (const float*)d_in[6];
  const float* o_w     = (const float*)d_in[7];
  float* out = (float*)d_out;

  char* ws = (char*)d_ws;
  size_t off = 0;
  auto alloc = [&](size_t bytes) {
    void* p = ws + off;
    off += (bytes + 255) & ~(size_t)255;
    return p;
  };
  const size_t MB = 1u << 20;
  short* hs_b   = (short*)alloc((size_t)SEQ * H * 2);
  // stacked q_a|kv_a, padded +64 rows so the n=16 tile of GEMM1 can overread
  // B safely (cols >= 2112 masked in epilogue)
  short* wab    = (short*)alloc((size_t)(QLR + KVAW_N + 64) * H * 2);
  short* qbw_b  = (short*)alloc((size_t)NQH * QLR * 2);
  short* kvbw_b = (short*)alloc((size_t)NKVC * KVLR * 2);
  short* ow_b   = (short*)alloc((size_t)H * NOV * 2);
  short* qhm    = (short*)alloc((size_t)NH * SEQ * QHD * 2);   // frag-major q
  short* kpeb   = (short*)alloc((size_t)SEQ * ROPED * 2);      // frag-major kpe
  short* knope  = (short*)alloc((size_t)NH * SEQ * NOPE * 2);  // frag-major k
  short* vT     = (short*)alloc((size_t)NH * VH * SEQ * 2);    // frag-major vT
  short* attnb  = (short*)alloc((size_t)SEQ * NOV * 2);
  char* R = (char*)alloc(36 * MB);
  float* qlat  = (float*)R;                 // 12.6 MB (phase 1-2)
  short* qlatn = (short*)(R + 13 * MB);     // 6.3 MB  (phase 2-3)
  short* kvln  = (short*)(R + 20 * MB);     // 2.1 MB  (phase 2-3)
  float* kvlp  = (float*)(R + 24 * MB);     // 4.7 MB  (phase 1-2)
  short* Opart = (short*)R;                 // 33.6 MB (attn)
  float2* mlb  = (float2*)(R + 34 * MB);    // 1.05 MB (attn)

  // small cvt: only the GEMM1 inputs (hs, q_a_w, kv_a_w)
  CvtArgs ca;
  ca.src[0] = hs;     ca.dst[0] = hs_b;
  ca.src[1] = q_a_w;  ca.dst[1] = wab;
  ca.src[2] = kv_a_w; ca.dst[2] = wab + (size_t)QLR * H;
  int sizes4[3] = { SEQ*H/4, QLR*H/4, KVAW_N*H/4 };
  ca.cum[0] = 0;
  for (int i = 0; i < 3; ++i) ca.cum[i+1] = ca.cum[i] + sizes4[i];
  k_cvt_all<<<1024, 256, 0, stream>>>(ca, ca.cum[3]);

  // big-weight cvt rides inside the GEMM1 launch (blocks 288..543)
  W3 w3;
  w3.src[0] = q_b_w;  w3.dst[0] = qbw_b;
  w3.src[1] = kv_b_w; w3.dst[1] = kvbw_b;
  w3.src[2] = o_w;    w3.dst[2] = ow_b;
  int wsz4[3] = { NQH*QLR/4, NKVC*KVLR/4, H*NOV/4 };
  w3.cum[0] = 0;
  for (int i = 0; i < 3; ++i) w3.cum[i+1] = w3.cum[i] + wsz4[i];
  W3 w3z = {};   // dummy for EPI=0

  // GEMM1: [qlat | kvlp] = hs @ [q_a_w; kv_a_w]^T
  // (288 gemm blocks XCD-patched + 256 converter blocks)
  k_gemm128<1><<<544, 256, 0, stream>>>(
      hs_b, wab, qlat, kvlp, QLR + KVAW_N, H, w3);
  // merged rms + rope_k
  k_rms2<<<2*SEQ, 256, 0, stream>>>(qlat, q_a_ln, qlatn, kvlp, kv_a_ln, kvln, kpeb);
  // GEMM2: q_b (fused rope+prescale -> qhm) + kv_b (-> knope, vT)  (896 blocks)
  k_gemm2<<<896, 256, 0, stream>>>(qlatn, qbw_b, kvln, kvbw_b, qhm, knope, vT);
  // attention (8-wave) + combine
  k_attn8<<<640, 512, 0, stream>>>(qhm, knope, kpeb, vT, Opart, mlb);
  k_comb<<<SEQ, 256, 0, stream>>>(Opart, mlb, attnb);
  // GEMM3: out = attn @ o_w^T  (256 blocks, XCD-patched)
  k_gemm128<0><<<256, 256, 0, stream>>>(
      attnb, ow_b, out, nullptr, H, NOV, w3z);
}

// Round 13
// 378.733 us; speedup vs baseline: 1.1035x; 1.1035x over previous
//
#include <hip/hip_runtime.h>
#include <cstdint>

#define H 2048
#define NH 16
#define QLR 1536
#define KVLR 512
#define NOPE 128
#define ROPED 64
#define VH 128
#define QHD 192
#define SEQ 2048
#define NQH (NH*QHD)        // 3072
#define NKVC (NH*(NOPE+VH)) // 4096
#define NOV (NH*VH)         // 2048
#define KVAW_N (KVLR+ROPED) // 576
#define SCALE_L2E 0.10411755f   // 192^-0.5 * log2(e)
#define NSEG 4

typedef __attribute__((ext_vector_type(8))) short short8;
typedef __attribute__((ext_vector_type(4))) short short4v;
typedef __attribute__((ext_vector_type(4))) float floatx4;

__device__ __forceinline__ short f2bf(float x) {
  unsigned u = __builtin_bit_cast(unsigned, x);
  unsigned r = (u + 0x7FFFu + ((u >> 16) & 1u)) >> 16;
  return (short)(unsigned short)r;
}
__device__ __forceinline__ float bf2f(short s) {
  unsigned u = ((unsigned)(unsigned short)s) << 16;
  return __builtin_bit_cast(float, u);
}
__device__ __forceinline__ void g2l16(const void* g, void* l) {
  __builtin_amdgcn_global_load_lds(
      (const __attribute__((address_space(1))) void*)(uintptr_t)(g),
      (__attribute__((address_space(3))) void*)(uintptr_t)(l),
      16, 0, 0);
}

// Fragment-major tile layouts (all 1KB tiles = 512 shorts, lane-major:
// offset = (quad_f*16 + l16_f)*8 + pos):
//   qhm  : [h][qt=128][ks=6]   q rows x 32-dim slices (prescaled, roped)
//   knope: [h][kt=128][ks=4]   kv rows x 32-dim slices (nope dims)
//   kpe  : [kt=128][2]         kv rows x 32-dim rope slices (head-shared)
//   vT   : [h][dt=8][kb=64]    16 d-rows x 32-kv slices (transposed V)

// ---------------- fused fp32 -> bf16 convert ----------------
struct CvtArgs {
  const float* src[6];
  short* dst[6];
  int cum[7];
};
__global__ __launch_bounds__(256) void k_cvt_all(CvtArgs a, int total4) {
  int stride = gridDim.x * 256;
  for (int i = blockIdx.x * 256 + threadIdx.x; i < total4; i += stride) {
    int j = 0;
#pragma unroll
    for (int t = 1; t < 6; ++t) j += (i >= a.cum[t]);
    int loc = i - a.cum[j];
    float4 v = ((const float4*)a.src[j])[loc];
    short4v o;
    o.x = f2bf(v.x); o.y = f2bf(v.y); o.z = f2bf(v.z); o.w = f2bf(v.w);
    ((short4v*)a.dst[j])[loc] = o;
  }
}

// ------- 128x128 pipelined NT GEMM (BK=32, 3-ring, XCD-patch swizzle) -------
// R6-proven configuration for GEMM1/GEMM3.
template<int EPI>
__global__ __launch_bounds__(256) void k_gemm128(
    const short* __restrict__ A, const short* __restrict__ B,
    float* __restrict__ C, float* __restrict__ C2, int N, int K)
{
  __shared__ short As[3][4096];
  __shared__ short Bs[3][4096];
  const int tid = threadIdx.x;
  const int lane = tid & 63;
  const int w = tid >> 6;
  const int wm = w & 1, wn = w >> 1;
  const int quad = lane >> 4, l16 = lane & 15;

  const int bid = blockIdx.x;
  const int xcd = bid & 7, j = bid >> 3;
  int mi_, ni_;
  if (EPI == 0) {          // 256 = 8 xcd x (4m x 8n)
    mi_ = (xcd & 3) * 4 + (j & 3);
    ni_ = (xcd >> 2) * 8 + (j >> 2);
  } else {                 // 288 = 8 xcd x (4m x 9n); n==17 idle
    mi_ = (xcd & 3) * 4 + (j & 3);
    ni_ = (xcd >> 2) * 9 + (j >> 2);
    if (ni_ >= 17) return;
  }
  const int m0 = mi_ * 128, n0 = ni_ * 128;
  const int T = K >> 5;

  floatx4 acc[4][4] = {};

  auto issue = [&](int t, int buf) {
#pragma unroll
    for (int i = 0; i < 2; ++i) {
      int c = i*256 + tid;
      int row = c & 127, koct = c >> 7;
      g2l16(A + (size_t)(m0 + row)*K + t*32 + koct*8, As[buf] + (koct*128 + row)*8);
      g2l16(B + (size_t)(n0 + row)*K + t*32 + koct*8, Bs[buf] + (koct*128 + row)*8);
    }
  };

  issue(0, 0);
  issue(1, 1);
  int buf = 0;
  for (int t = 0; t < T; ++t) {
    if (t + 2 < T) {
      int nb = buf - 1; if (nb < 0) nb = 2;
      issue(t + 2, nb);
      asm volatile("s_waitcnt vmcnt(8)" ::: "memory");
    } else if (t + 1 < T) {
      asm volatile("s_waitcnt vmcnt(4)" ::: "memory");
    } else {
      asm volatile("s_waitcnt vmcnt(0)" ::: "memory");
    }
    asm volatile("s_barrier" ::: "memory");
    short8 af[4], bfr[4];
#pragma unroll
    for (int mi = 0; mi < 4; ++mi)
      af[mi] = *(const short8*)(As[buf] + (quad*128 + wm*64 + mi*16 + l16)*8);
#pragma unroll
    for (int ni = 0; ni < 4; ++ni)
      bfr[ni] = *(const short8*)(Bs[buf] + (quad*128 + wn*64 + ni*16 + l16)*8);
#pragma unroll
    for (int mi = 0; mi < 4; ++mi)
#pragma unroll
      for (int ni = 0; ni < 4; ++ni)
        acc[mi][ni] = __builtin_amdgcn_mfma_f32_16x16x32_bf16(af[mi], bfr[ni], acc[mi][ni], 0, 0, 0);
    asm volatile("s_barrier" ::: "memory");
    buf = buf + 1; if (buf > 2) buf = 0;
  }

#pragma unroll
  for (int mi = 0; mi < 4; ++mi) {
#pragma unroll
    for (int ni = 0; ni < 4; ++ni) {
      int col = n0 + wn*64 + ni*16 + l16;
#pragma unroll
      for (int r = 0; r < 4; ++r) {
        int row = m0 + wm*64 + mi*16 + quad*4 + r;
        if (EPI == 0) {
          C[(size_t)row*N + col] = acc[mi][ni][r];
        } else {
          if (col < QLR)                C[(size_t)row*QLR + col] = acc[mi][ni][r];
          else if (col < QLR + KVAW_N)  C2[(size_t)row*KVAW_N + (col - QLR)] = acc[mi][ni][r];
        }
      }
    }
  }
}

// -------- merged q_b + kv_b GEMM (BN=128, 3-ring, XCD-patch swizzle) --------
// R8-proven 2-barrier version.
// q part (384 = 8 x 4m x 12n), kv part (512 = 8 x 4m x 16n).
__global__ __launch_bounds__(256) void k_gemm2(
    const short* __restrict__ qlatn, const short* __restrict__ qbw,
    const short* __restrict__ kvln,  const short* __restrict__ kvbw,
    short* __restrict__ qhm, short* __restrict__ knope, short* __restrict__ vTd)
{
  __shared__ short As[3][4096];
  __shared__ short Bs[3][4096];
  const int tid = threadIdx.x;
  const int lane = tid & 63;
  const int w = tid >> 6;
  const int wm = w & 1, wn = w >> 1;
  const int quad = lane >> 4, l16 = lane & 15;
  int bid = blockIdx.x;
  const short *A, *B; int K, m0, n0; bool isq;
  if (bid < 384) {
    isq = true;  A = qlatn; B = qbw;  K = QLR;
    const int xcd = bid & 7, j = bid >> 3;          // j 0..47
    m0 = ((xcd & 3) * 4 + (j & 3)) * 128;           // m 0..15
    n0 = ((xcd >> 2) * 12 + (j >> 2)) * 128;        // n 0..23
  } else {
    int b2 = bid - 384; isq = false; A = kvln; B = kvbw; K = KVLR;
    const int xcd = b2 & 7, j = b2 >> 3;            // j 0..63
    m0 = ((xcd & 3) * 4 + (j & 3)) * 128;           // m 0..15
    n0 = ((xcd >> 2) * 16 + (j >> 2)) * 128;        // n 0..31
  }
  const int T = K >> 5;

  floatx4 acc[4][4] = {};

  auto issue = [&](int t, int buf) {
#pragma unroll
    for (int i = 0; i < 2; ++i) {
      int c = i*256 + tid;
      int row = c & 127, koct = c >> 7;
      g2l16(A + (size_t)(m0 + row)*K + t*32 + koct*8, As[buf] + (koct*128 + row)*8);
      g2l16(B + (size_t)(n0 + row)*K + t*32 + koct*8, Bs[buf] + (koct*128 + row)*8);
    }
  };

  issue(0, 0);
  issue(1, 1);
  int buf = 0;
  for (int t = 0; t < T; ++t) {
    if (t + 2 < T) {
      int nb = buf - 1; if (nb < 0) nb = 2;
      issue(t + 2, nb);
      asm volatile("s_waitcnt vmcnt(8)" ::: "memory");
    } else if (t + 1 < T) {
      asm volatile("s_waitcnt vmcnt(4)" ::: "memory");
    } else {
      asm volatile("s_waitcnt vmcnt(0)" ::: "memory");
    }
    asm volatile("s_barrier" ::: "memory");
    short8 af[4], bfr[4];
#pragma unroll
    for (int mi = 0; mi < 4; ++mi)
      af[mi] = *(const short8*)(As[buf] + (quad*128 + wm*64 + mi*16 + l16)*8);
#pragma unroll
    for (int ni = 0; ni < 4; ++ni)
      bfr[ni] = *(const short8*)(Bs[buf] + (quad*128 + wn*64 + ni*16 + l16)*8);
#pragma unroll
    for (int mi = 0; mi < 4; ++mi)
#pragma unroll
      for (int ni = 0; ni < 4; ++ni)
        acc[mi][ni] = __builtin_amdgcn_mfma_f32_16x16x32_bf16(af[mi], bfr[ni], acc[mi][ni], 0, 0, 0);
    asm volatile("s_barrier" ::: "memory");
    buf = buf + 1; if (buf > 2) buf = 0;
  }

  const int n064 = n0 + wn * 64;
  if (isq) {
    const int h = n064 / QHD;
    const bool ropew = (n064 % QHD) == 128;
    if (!ropew) {
      const int dbase = n064 - h * QHD;   // 0 or 64
#pragma unroll
      for (int mi = 0; mi < 4; ++mi) {
        const int qt = (m0 + wm*64 + mi*16) >> 4;
#pragma unroll
        for (int ni = 0; ni < 4; ++ni) {
          int d = dbase + ni*16 + l16;
          size_t tb = ((size_t)(h*128 + qt)*6 + (d>>5))*512
                    + (size_t)(((d>>3)&3)*16)*8 + (d&7);
#pragma unroll
          for (int r = 0; r < 4; ++r)
            qhm[tb + (quad*4 + r)*8] = f2bf(acc[mi][ni][r] * SCALE_L2E);
        }
      }
    } else {
#pragma unroll
      for (int ni = 0; ni < 2; ++ni) {
        int i = ni*16 + l16;                     // 0..31
        float fr = powf(10000.0f, -(float)i / 32.0f);
        const int qoff = ((i>>3)*16)*8 + (i&7);
#pragma unroll
        for (int mi = 0; mi < 4; ++mi) {
          const int qt = (m0 + wm*64 + mi*16) >> 4;
          size_t t4 = ((size_t)(h*128 + qt)*6 + 4)*512 + qoff;  // ks=4 (dims 128..159)
#pragma unroll
          for (int r = 0; r < 4; ++r) {
            int row = m0 + wm*64 + mi*16 + quad*4 + r;
            float ang = (float)row * fr;
            float cv, sv; __sincosf(ang, &sv, &cv);
            float x1 = acc[mi][ni][r], x2 = acc[mi][ni+2][r];
            qhm[t4 + (quad*4 + r)*8]       = f2bf((x1*cv - x2*sv) * SCALE_L2E);
            qhm[t4 + 512 + (quad*4 + r)*8] = f2bf((x2*cv + x1*sv) * SCALE_L2E); // ks=5
          }
        }
      }
    }
  } else {
    const bool isv = (n064 & 128) != 0;
    if (!isv) {
#pragma unroll
      for (int mi = 0; mi < 4; ++mi) {
        const int kt = (m0 + wm*64 + mi*16) >> 4;
#pragma unroll
        for (int ni = 0; ni < 4; ++ni) {
          int col = n064 + ni*16 + l16;
          int hh = col >> 8, d = col & 127;
          size_t tb = ((size_t)(hh*128 + kt)*4 + (d>>5))*512
                    + (size_t)(((d>>3)&3)*16)*8 + (d&7);
#pragma unroll
          for (int r = 0; r < 4; ++r)
            knope[tb + (quad*4 + r)*8] = f2bf(acc[mi][ni][r]);
        }
      }
    } else {
#pragma unroll
      for (int mi = 0; mi < 4; ++mi) {
        const int row0 = m0 + wm*64 + mi*16 + quad*4;   // kv row of r=0
        const int kb = row0 >> 5;
        const int voff = (((row0>>3)&3)*16)*8 + (row0 & 7); // row0%8 in {0,4}
#pragma unroll
        for (int ni = 0; ni < 4; ++ni) {
          int col = n064 + ni*16 + l16;
          int hh = col >> 8, dv = (col & 255) - 128;
          short4v pk;
          pk.x = f2bf(acc[mi][ni][0]); pk.y = f2bf(acc[mi][ni][1]);
          pk.z = f2bf(acc[mi][ni][2]); pk.w = f2bf(acc[mi][ni][3]);
          *(short4v*)(vTd + ((size_t)(hh*8 + (dv>>4))*64 + kb)*512
                          + voff + (dv & 15)*8) = pk;
        }
      }
    }
  }
}

// ---------------- merged RMS norms + rope_k ----------------
__global__ __launch_bounds__(256) void k_rms2(
    const float* __restrict__ qlat, const float* __restrict__ q_a_ln,
    short* __restrict__ qlatn,
    const float* __restrict__ kvlp, const float* __restrict__ kv_a_ln,
    short* __restrict__ kvln, short* __restrict__ kpe)
{
  int b = blockIdx.x;
  __shared__ float red[4];
  if (b < SEQ) {
    int row = b;
    const float* xr = qlat + (size_t)row * QLR;
    float s = 0.f;
    for (int i = threadIdx.x; i < QLR; i += 256) { float v = xr[i]; s += v*v; }
#pragma unroll
    for (int off = 1; off < 64; off <<= 1) s += __shfl_xor(s, off);
    if ((threadIdx.x & 63) == 0) red[threadIdx.x >> 6] = s;
    __syncthreads();
    float inv = rsqrtf((red[0]+red[1]+red[2]+red[3]) / (float)QLR + 1e-6f);
    for (int i = threadIdx.x; i < QLR; i += 256)
      qlatn[(size_t)row * QLR + i] = f2bf(xr[i] * inv * q_a_ln[i]);
  } else {
    int row = b - SEQ;
    const float* xr = kvlp + (size_t)row * KVAW_N;
    float s = 0.f;
    for (int i = threadIdx.x; i < KVLR; i += 256) { float v = xr[i]; s += v*v; }
#pragma unroll
    for (int off = 1; off < 64; off <<= 1) s += __shfl_xor(s, off);
    if ((threadIdx.x & 63) == 0) red[threadIdx.x >> 6] = s;
    __syncthreads();
    float inv = rsqrtf((red[0]+red[1]+red[2]+red[3]) / (float)KVLR + 1e-6f);
    for (int i = threadIdx.x; i < KVLR; i += 256)
      kvln[(size_t)row * KVLR + i] = f2bf(xr[i] * inv * kv_a_ln[i]);
    if (threadIdx.x < 32) {
      int i = threadIdx.x;
      float ang = (float)row * powf(10000.0f, -(float)i / 32.0f);
      float cv, sv; __sincosf(ang, &sv, &cv);
      float x1 = xr[KVLR + i], x2 = xr[KVLR + 32 + i];
      // fragment-major kpe: tile (row>>4)*2 + slice, lane (i>>3, row&15), pos i&7
      size_t t0 = (size_t)((row >> 4) * 2) * 512
                + (size_t)(((i >> 3) * 16) + (row & 15)) * 8 + (i & 7);
      kpe[t0]       = f2bf(x1*cv - x2*sv);   // slice 0: dims 0..31
      kpe[t0 + 512] = f2bf(x2*cv + x1*sv);   // slice 1: dims 32..63
    }
  }
}

// ------------- attention v9: 8-wave cooperative LDS-staged flash -------------
// 640 blocks; 8 waves x 16 q-rows (512 thr); K/kpe/V staged cooperatively via
// global_load_lds, double-buffered, prefetched 2 chunks ahead (counted vmcnt);
// defer-max (T13) skips the O-rescale when chunk max grew <= 8.
__device__ __constant__ unsigned char g_task[40] = {
  60,61,62,63, 56,57,58, 52,53,54, 48,49,50, 44,45,46,
  40,41, 36,37, 32,33, 28,29, 24, 20, 16, 12,
  59,42,25,8, 55,38,21,4, 51,34,17,0 };

__global__ __launch_bounds__(512) void k_attn8(
    const short* __restrict__ qhm,   // frag-major [NH][128][6] tiles, prescaled
    const short* __restrict__ knope, // frag-major [NH][128][4] tiles
    const short* __restrict__ kpe,   // frag-major [128][2] tiles
    const short* __restrict__ vT,    // frag-major [NH][8][64] tiles
    short* __restrict__ Opart,       // [NSEG][SEQ][NOV]
    float2* __restrict__ mlb)        // [NSEG][SEQ][NH]
{
  // LDS: 2 chunk buffers of 40KB (K 8192 | kpe 4096 | V 8192 shorts) + P.
  __shared__ short Ls[2][20480];
  __shared__ short Pl[8][16 * 72];
  const int tid = threadIdx.x;
  const int lane = tid & 63, w = tid >> 6;   // w 0..7
  const int quad = lane >> 4, l16 = lane & 15;
  const int b = blockIdx.x;
  const int h = b & 15;                 // head -> XCD-locked L2 locality
  const int qs2 = g_task[b >> 4];
  const int qb = qs2 >> 2, seg = qs2 & 3;
  const int cs = seg * 8;               // chunks of 64 kv
  const int cend0 = 2 * qb + 2;
  const int cend = (cend0 < cs + 8) ? cend0 : (cs + 8);
  const int qws = qb * 128 + w * 16;    // 16 q-rows per wave
  short* Plw = Pl[w];

  const short* qbase = qhm   + (size_t)h * (128*6*512);
  const short* kbase = knope + (size_t)h * (128*4*512);
  const short* vbase = vT    + (size_t)h * (8*64*512);

  const int qt0 = qws >> 4;             // q-tile index (16 rows)
  short8 qf[6];
#pragma unroll
  for (int ks = 0; ks < 6; ++ks)
    qf[ks] = *(const short8*)(qbase + ((size_t)qt0*6 + ks)*512 + lane*8);

  // stage chunk kc into buffer buf: 5 x 16B per thread (512 threads)
  auto issue = [&](int kc, int buf) {
    short* L = &Ls[buf][0];
    const short* ksrc = kbase + (size_t)kc * 8192;   // 4 kt-tiles x 4 slices
    const short* psrc = kpe   + (size_t)kc * 4096;   // 4 kt-tiles x 2 slices
#pragma unroll
    for (int i = 0; i < 2; ++i)
      g2l16(ksrc + (i*512 + tid)*8, L + (i*512 + tid)*8);
    g2l16(psrc + tid*8, L + 8192 + tid*8);
#pragma unroll
    for (int i = 0; i < 2; ++i) {
      int uv = i*512 + tid;
      int dt = uv >> 7, wi = uv & 127;
      g2l16(vbase + ((size_t)(dt*64 + kc*2))*512 + wi*8, L + 12288 + uv*8);
    }
  };

  issue(cs, 0);
  if (cs + 1 < cend) issue(cs + 1, 1);

  floatx4 oacc[8] = {};
  float m_i = -1e30f, l_i = 0.f;

  for (int kc = cs; kc < cend; ++kc) {
    if (kc + 1 < cend) asm volatile("s_waitcnt vmcnt(5)" ::: "memory");
    else               asm volatile("s_waitcnt vmcnt(0)" ::: "memory");
    asm volatile("s_barrier" ::: "memory");
    const short* Lb = &Ls[kc & 1][0];
    const int kv0 = kc * 64;

    // ---- S^T over 4 sub-tiles of 16 kv (one 16-row q tile) ----
    floatx4 s[4] = {};
#pragma unroll
    for (int mt = 0; mt < 4; ++mt) {
      const short* kr = Lb + mt*2048 + lane*8;
      const short* pr = Lb + 8192 + mt*1024 + lane*8;
      short8 kf0 = *(const short8*)(kr);
      short8 kf1 = *(const short8*)(kr + 512);
      short8 kf2 = *(const short8*)(kr + 1024);
      short8 kf3 = *(const short8*)(kr + 1536);
      short8 kf4 = *(const short8*)(pr);
      short8 kf5 = *(const short8*)(pr + 512);
      s[mt] = __builtin_amdgcn_mfma_f32_16x16x32_bf16(kf0, qf[0], s[mt], 0, 0, 0);
      s[mt] = __builtin_amdgcn_mfma_f32_16x16x32_bf16(kf1, qf[1], s[mt], 0, 0, 0);
      s[mt] = __builtin_amdgcn_mfma_f32_16x16x32_bf16(kf2, qf[2], s[mt], 0, 0, 0);
      s[mt] = __builtin_amdgcn_mfma_f32_16x16x32_bf16(kf3, qf[3], s[mt], 0, 0, 0);
      s[mt] = __builtin_amdgcn_mfma_f32_16x16x32_bf16(kf4, qf[4], s[mt], 0, 0, 0);
      s[mt] = __builtin_amdgcn_mfma_f32_16x16x32_bf16(kf5, qf[5], s[mt], 0, 0, 0);
    }

    // ---- softmax for the 64 kv (defer-max) ----
    const bool diag = (kv0 + 64 > qws);
    const int qg = qws + l16;
    float mx = -1e30f;
#pragma unroll
    for (int mt = 0; mt < 4; ++mt)
#pragma unroll
      for (int rr = 0; rr < 4; ++rr) {
        float v = s[mt][rr];
        if (diag) {
          int kvg = kv0 + mt*16 + quad*4 + rr;
          v = (kvg <= qg) ? v : -1e30f;
          s[mt][rr] = v;
        }
        mx = fmaxf(mx, v);
      }
    mx = fmaxf(mx, __shfl_xor(mx, 16));
    mx = fmaxf(mx, __shfl_xor(mx, 32));
    const bool skip = __all(mx - m_i <= 8.0f);   // wave-uniform
    float alpha = 1.0f;
    if (!skip) {
      float mnew = fmaxf(m_i, mx);
      alpha = exp2f(m_i - mnew);
      m_i = mnew;
    }
    float ssum = 0.f;
#pragma unroll
    for (int mt = 0; mt < 4; ++mt) {
      float p0 = exp2f(s[mt][0] - m_i);
      float p1 = exp2f(s[mt][1] - m_i);
      float p2 = exp2f(s[mt][2] - m_i);
      float p3 = exp2f(s[mt][3] - m_i);
      ssum += (p0 + p1) + (p2 + p3);
      short4v pk; pk.x = f2bf(p0); pk.y = f2bf(p1); pk.z = f2bf(p2); pk.w = f2bf(p3);
      *(short4v*)(Plw + l16*72 + mt*16 + quad*4) = pk;
    }
    ssum += __shfl_xor(ssum, 16);
    ssum += __shfl_xor(ssum, 32);
    l_i = l_i * alpha + ssum;
    if (!skip) {
#pragma unroll
      for (int dt = 0; dt < 8; ++dt)
#pragma unroll
        for (int rr = 0; rr < 4; ++rr) oacc[dt][rr] *= alpha;
    }

    // ---- O^T += V^T * P^T over 2 slices of 32 kv ----
#pragma unroll
    for (int sl = 0; sl < 2; ++sl) {
      short8 pf = *(const short8*)(Plw + l16*72 + sl*32 + quad*8);
#pragma unroll
      for (int dt = 0; dt < 8; ++dt) {
        short8 vf = *(const short8*)(Lb + 12288 + (dt*2 + sl)*512 + lane*8);
        oacc[dt] = __builtin_amdgcn_mfma_f32_16x16x32_bf16(vf, pf, oacc[dt], 0, 0, 0);
      }
    }

    asm volatile("s_barrier" ::: "memory");   // all waves done reading buf
    if (kc + 2 < cend) issue(kc + 2, kc & 1);
  }

  {
    float inv = (l_i > 0.f) ? 1.f / l_i : 0.f;
    int q = qws + l16;
    if (quad == 0)
      mlb[((size_t)seg * SEQ + q) * NH + h] = make_float2(m_i, l_i);
#pragma unroll
    for (int dt = 0; dt < 8; ++dt) {
      short4v pk;
      pk.x = f2bf(oacc[dt][0] * inv);
      pk.y = f2bf(oacc[dt][1] * inv);
      pk.z = f2bf(oacc[dt][2] * inv);
      pk.w = f2bf(oacc[dt][3] * inv);
      *(short4v*)(Opart + ((size_t)seg * SEQ + q) * NOV + h * VH + dt*16 + quad*4) = pk;
    }
  }
}

// ---------------- split-KV combiner ----------------
__global__ __launch_bounds__(256) void k_comb(
    const short* __restrict__ Opart, const float2* __restrict__ mlb,
    short* __restrict__ ob)
{
  int q = blockIdx.x;
  int hd0 = threadIdx.x * 8;
  int h = hd0 >> 7;
  int nact = (q >> 9) + 1;
  float2 mlv[NSEG];
  float M = -1e30f;
  for (int s = 0; s < nact; ++s) {
    mlv[s] = mlb[((size_t)s * SEQ + q) * NH + h];
    M = fmaxf(M, mlv[s].x);
  }
  float wgt[NSEG]; float L = 0.f;
  for (int s = 0; s < nact; ++s) {
    wgt[s] = mlv[s].y * exp2f(mlv[s].x - M);
    L += wgt[s];
  }
  float invL = 1.0f / L;
  float acc[8] = {};
  for (int s = 0; s < nact; ++s) {
    short8 o = *(const short8*)(Opart + ((size_t)s * SEQ + q) * NOV + hd0);
    float ws = wgt[s] * invL;
#pragma unroll
    for (int j = 0; j < 8; ++j) acc[j] += ws * bf2f(o[j]);
  }
  short8 rr;
#pragma unroll
  for (int j = 0; j < 8; ++j) rr[j] = f2bf(acc[j]);
  *(short8*)(ob + (size_t)q * NOV + hd0) = rr;
}

// ---------------- launch ----------------
extern "C" void kernel_launch(void* const* d_in, const int* in_sizes, int n_in,
                              void* d_out, int out_size, void* d_ws, size_t ws_size,
                              hipStream_t stream) {
  const float* hs      = (const float*)d_in[0];
  const float* q_a_w   = (const float*)d_in[1];
  const float* q_a_ln  = (const float*)d_in[2];
  const float* q_b_w   = (const float*)d_in[3];
  const float* kv_a_w  = (const float*)d_in[4];
  const float* kv_a_ln = (const float*)d_in[5];
  const float* kv_b_w  = (const float*)d_in[6];
  const float* o_w     = (const float*)d_in[7];
  float* out = (float*)d_out;

  char* ws = (char*)d_ws;
  size_t off = 0;
  auto alloc = [&](size_t bytes) {
    void* p = ws + off;
    off += (bytes + 255) & ~(size_t)255;
    return p;
  };
  const size_t MB = 1u << 20;
  short* hs_b   = (short*)alloc((size_t)SEQ * H * 2);
  // stacked q_a|kv_a, padded +64 rows so the n=16 tile of GEMM1 can overread
  // B safely (cols >= 2112 masked in epilogue)
  short* wab    = (short*)alloc((size_t)(QLR + KVAW_N + 64) * H * 2);
  short* qbw_b  = (short*)alloc((size_t)NQH * QLR * 2);
  short* kvbw_b = (short*)alloc((size_t)NKVC * KVLR * 2);
  short* ow_b   = (short*)alloc((size_t)H * NOV * 2);
  short* qhm    = (short*)alloc((size_t)NH * SEQ * QHD * 2);   // frag-major q
  short* kpeb   = (short*)alloc((size_t)SEQ * ROPED * 2);      // frag-major kpe
  short* knope  = (short*)alloc((size_t)NH * SEQ * NOPE * 2);  // frag-major k
  short* vT     = (short*)alloc((size_t)NH * VH * SEQ * 2);    // frag-major vT
  short* attnb  = (short*)alloc((size_t)SEQ * NOV * 2);
  char* R = (char*)alloc(36 * MB);
  float* qlat  = (float*)R;                 // 12.6 MB (phase 1-2)
  short* qlatn = (short*)(R + 13 * MB);     // 6.3 MB  (phase 2-3)
  short* kvln  = (short*)(R + 20 * MB);     // 2.1 MB  (phase 2-3)
  float* kvlp  = (float*)(R + 24 * MB);     // 4.7 MB  (phase 1-2)
  short* Opart = (short*)R;                 // 33.6 MB (attn)
  float2* mlb  = (float2*)(R + 34 * MB);    // 1.05 MB (attn)

  CvtArgs ca;
  ca.src[0] = hs;     ca.dst[0] = hs_b;
  ca.src[1] = q_a_w;  ca.dst[1] = wab;
  ca.src[2] = kv_a_w; ca.dst[2] = wab + (size_t)QLR * H;
  ca.src[3] = q_b_w;  ca.dst[3] = qbw_b;
  ca.src[4] = kv_b_w; ca.dst[4] = kvbw_b;
  ca.src[5] = o_w;    ca.dst[5] = ow_b;
  int sizes4[6] = { SEQ*H/4, QLR*H/4, KVAW_N*H/4, NQH*QLR/4, NKVC*KVLR/4, H*NOV/4 };
  ca.cum[0] = 0;
  for (int i = 0; i < 6; ++i) ca.cum[i+1] = ca.cum[i] + sizes4[i];
  k_cvt_all<<<2048, 256, 0, stream>>>(ca, ca.cum[6]);

  // GEMM1: [qlat | kvlp] = hs @ [q_a_w; kv_a_w]^T  (288 blocks, XCD-patched)
  k_gemm128<1><<<288, 256, 0, stream>>>(
      hs_b, wab, qlat, kvlp, QLR + KVAW_N, H);
  // merged rms + rope_k
  k_rms2<<<2*SEQ, 256, 0, stream>>>(qlat, q_a_ln, qlatn, kvlp, kv_a_ln, kvln, kpeb);
  // GEMM2: q_b (fused rope+prescale -> qhm) + kv_b (-> knope, vT)  (896 blocks)
  k_gemm2<<<896, 256, 0, stream>>>(qlatn, qbw_b, kvln, kvbw_b, qhm, knope, vT);
  // attention (8-wave) + combine
  k_attn8<<<640, 512, 0, stream>>>(qhm, knope, kpeb, vT, Opart, mlb);
  k_comb<<<SEQ, 256, 0, stream>>>(Opart, mlb, attnb);
  // GEMM3: out = attn @ o_w^T  (256 blocks, XCD-patched)
  k_gemm128<0><<<256, 256, 0, stream>>>(
      attnb, ow_b, out, nullptr, H, NOV);
}